// Round 1
// baseline (114.038 us; speedup 1.0000x reference)
//
#include <hip/hip_runtime.h>
#include <math.h>

#define NBINS 10

// Pass 1: per-block partial {bce-sum, valid-count} per bin.
// loss = (1/n_nonempty) * sum_b S_b / cnt_b   (tot cancels; weight is 0/1)
__global__ __launch_bounds__(256) void ghmc_partials(
    const float* __restrict__ pred,
    const int*   __restrict__ target,
    const float* __restrict__ weight,
    float* __restrict__ ws_sum,   // [NBINS * NB]
    int*   __restrict__ ws_cnt,   // [NBINS * NB]
    long long n, int NB)
{
  float sum[NBINS];
  int   cnt[NBINS];
#pragma unroll
  for (int b = 0; b < NBINS; b++) { sum[b] = 0.0f; cnt[b] = 0; }

  const long long nv4    = n >> 2;
  const long long stride = (long long)gridDim.x * blockDim.x;
  long long idx = (long long)blockIdx.x * blockDim.x + threadIdx.x;

  const float4* p4 = (const float4*)pred;
  const int4*   t4 = (const int4*)target;
  const float4* w4 = (const float4*)weight;

  for (long long i = idx; i < nv4; i += stride) {
    float4 p = p4[i];
    int4   t = t4[i];
    float4 w = w4[i];
#pragma unroll
    for (int j = 0; j < 4; j++) {
      float pj = (&p.x)[j];
      float tj = (float)((&t.x)[j]);
      float wj = (&w.x)[j];
      // q = exp(-|p|); sigmoid(|p|) = 1/(1+q); sigmoid(-|p|) = q/(1+q)
      float q = __expf(-fabsf(pj));
      float r = __builtin_amdgcn_rcpf(1.0f + q);
      // g = |sigmoid(p) - t| = sigmoid((1-2t)*p)
      float arg = (1.0f - 2.0f * tj) * pj;
      float g = (arg >= 0.0f) ? r : (q * r);
      // stable BCE-with-logits
      float bce = fmaxf(pj, 0.0f) - pj * tj + __logf(1.0f + q);
      int bin = (wj > 0.0f) ? min((int)(g * 10.0f), NBINS - 1) : -1;
#pragma unroll
      for (int b = 0; b < NBINS; b++) {
        bool m = (bin == b);
        cnt[b] += m ? 1 : 0;
        sum[b] += m ? bce : 0.0f;
      }
    }
  }

  // scalar tail (n % 4), done by one thread (zero iters for this problem)
  if (idx == 0) {
    for (long long i = (nv4 << 2); i < n; i++) {
      float pj = pred[i];
      float tj = (float)target[i];
      float wj = weight[i];
      float q = __expf(-fabsf(pj));
      float r = __builtin_amdgcn_rcpf(1.0f + q);
      float arg = (1.0f - 2.0f * tj) * pj;
      float g = (arg >= 0.0f) ? r : (q * r);
      float bce = fmaxf(pj, 0.0f) - pj * tj + __logf(1.0f + q);
      int bin = (wj > 0.0f) ? min((int)(g * 10.0f), NBINS - 1) : -1;
#pragma unroll
      for (int b = 0; b < NBINS; b++) {
        bool m = (bin == b);
        cnt[b] += m ? 1 : 0;
        sum[b] += m ? bce : 0.0f;
      }
    }
  }

  // block reduction: wave shuffle -> LDS atomics (few per block) -> ws
  __shared__ float s_sum[NBINS];
  __shared__ int   s_cnt[NBINS];
  if (threadIdx.x < NBINS) { s_sum[threadIdx.x] = 0.0f; s_cnt[threadIdx.x] = 0; }
  __syncthreads();
  int lane = threadIdx.x & 63;
#pragma unroll
  for (int b = 0; b < NBINS; b++) {
    float v = sum[b];
    int   c = cnt[b];
    for (int off = 32; off >= 1; off >>= 1) {
      v += __shfl_down(v, off);
      c += __shfl_down(c, off);
    }
    if (lane == 0) {
      atomicAdd(&s_sum[b], v);
      atomicAdd(&s_cnt[b], c);
    }
  }
  __syncthreads();
  if (threadIdx.x < NBINS) {
    ws_sum[threadIdx.x * NB + blockIdx.x] = s_sum[threadIdx.x];
    ws_cnt[threadIdx.x * NB + blockIdx.x] = s_cnt[threadIdx.x];
  }
}

// Pass 2: reduce NB partials per bin, compute scalar loss. Deterministic.
__global__ __launch_bounds__(256) void ghmc_finalize(
    const float* __restrict__ ws_sum,
    const int*   __restrict__ ws_cnt,
    float* __restrict__ out, int NB)
{
  float ls[NBINS];
  int   lc[NBINS];
#pragma unroll
  for (int b = 0; b < NBINS; b++) { ls[b] = 0.0f; lc[b] = 0; }

  for (int i = threadIdx.x; i < NB; i += 256) {
#pragma unroll
    for (int b = 0; b < NBINS; b++) {
      ls[b] += ws_sum[b * NB + i];
      lc[b] += ws_cnt[b * NB + i];
    }
  }

  __shared__ float ssum[NBINS][4];
  __shared__ int   scnt[NBINS][4];
  int lane = threadIdx.x & 63, wid = threadIdx.x >> 6;
#pragma unroll
  for (int b = 0; b < NBINS; b++) {
    float v = ls[b];
    int   c = lc[b];
    for (int off = 32; off >= 1; off >>= 1) {
      v += __shfl_down(v, off);
      c += __shfl_down(c, off);
    }
    if (lane == 0) { ssum[b][wid] = v; scnt[b][wid] = c; }
  }
  __syncthreads();

  if (threadIdx.x == 0) {
    int n_ne = 0;
    float sums[NBINS];
    float cnts[NBINS];
#pragma unroll
    for (int b = 0; b < NBINS; b++) {
      float v = 0.0f;
      int   c = 0;
      for (int w = 0; w < 4; w++) { v += ssum[b][w]; c += scnt[b][w]; }
      sums[b] = v;
      cnts[b] = (float)c;
      n_ne += (c > 0) ? 1 : 0;
    }
    float nne = (n_ne > 0) ? (float)n_ne : 1.0f;
    float loss = 0.0f;
#pragma unroll
    for (int b = 0; b < NBINS; b++) {
      if (cnts[b] > 0.0f) loss += sums[b] / (cnts[b] * nne);
    }
    out[0] = loss;  // LOSS_WEIGHT = 1.0
  }
}

extern "C" void kernel_launch(void* const* d_in, const int* in_sizes, int n_in,
                              void* d_out, int out_size, void* d_ws, size_t ws_size,
                              hipStream_t stream)
{
  const float* pred   = (const float*)d_in[0];
  const int*   target = (const int*)d_in[1];
  const float* weight = (const float*)d_in[2];
  float* out = (float*)d_out;
  long long n = (long long)in_sizes[0];

  int NB = 2048;
  size_t per_block = (size_t)NBINS * (sizeof(float) + sizeof(int));
  if (ws_size < (size_t)NB * per_block) {
    int maxnb = (int)(ws_size / per_block);
    NB = (maxnb < 1) ? 1 : maxnb;
  }
  float* ws_sum = (float*)d_ws;
  int*   ws_cnt = (int*)((char*)d_ws + (size_t)NBINS * NB * sizeof(float));

  ghmc_partials<<<NB, 256, 0, stream>>>(pred, target, weight, ws_sum, ws_cnt, n, NB);
  ghmc_finalize<<<1, 256, 0, stream>>>(ws_sum, ws_cnt, out, NB);
}